// Round 2
// baseline (227.960 us; speedup 1.0000x reference)
//
#include <hip/hip_runtime.h>

// PrototypicalNetworkModel on MI355X.
// Pipeline: W^T->bf16 transpose | bf16-MFMA GEMM (query+support stacked,
// m97-style: gload_lds B + reg-staged cvt A, T2 XOR-swizzled LDS, BK=64) |
// prototype median+mean | per-row stats + bf16 cast | cross-GEMM with fused
// sqrt-distance epilogue.

typedef unsigned short u16;
typedef __attribute__((ext_vector_type(4))) unsigned short u16x4;
typedef __attribute__((ext_vector_type(8))) unsigned short u16x8;
typedef __attribute__((ext_vector_type(8))) short bf16x8;   // 8 bf16 (4 VGPRs)
typedef __attribute__((ext_vector_type(4))) float f32x4;

#define N_QUERY 8192
#define F_IN    4096
#define D_EMB   1024
#define N_SUP   1000
#define N_WAY   100
#define BK      64

__device__ __forceinline__ u16 f2b(float f) {   // f32 -> bf16 RNE
  unsigned int u = __builtin_bit_cast(unsigned int, f);
  u += 0x7FFFu + ((u >> 16) & 1u);
  return (u16)(u >> 16);
}

#define GLB_PTR(p) ((const __attribute__((address_space(1))) unsigned int*)(p))
#define LDS_PTR(p) ((__attribute__((address_space(3))) unsigned int*)(p))

// ---------------- W [4096][1024] f32 -> Wt [1024][4096] bf16 ----------------
__global__ __launch_bounds__(256) void wt_k(const float* __restrict__ W,
                                            u16* __restrict__ Wt) {
  __shared__ float tile[32][33];
  int kb = blockIdx.x * 32, nb = blockIdx.y * 32;
  int tx = threadIdx.x & 31, ty = threadIdx.x >> 5;
#pragma unroll
  for (int i = 0; i < 4; ++i) {
    int k = ty + i * 8;
    tile[k][tx] = W[(size_t)(kb + k) * D_EMB + nb + tx];
  }
  __syncthreads();
#pragma unroll
  for (int i = 0; i < 4; ++i) {
    int n = ty + i * 8;
    Wt[(size_t)(nb + n) * F_IN + kb + tx] = f2b(tile[tx][n]);
  }
}

// ---------------- GEMM1: Z[9216][1024] = A[9216][4096] @ W + b -------------
// A rows: [0,8192) = query, [8192, 9192) = support, rest clamped (unused).
// LDS: [128 rows][64 bf16] = 128B row stride, storage swizzle
//   storage_byte = row*128 + (col_byte ^ ((row&7)<<4))     (T2)
// gload_lds (B) writes linear chunks -> global source pre-inverse-swizzled.
// A is f32: load -> cvt -> ds_write_b128 at linear (chunk-ordered) offsets.
__global__ __launch_bounds__(256) void gemm1_k(
    const float* __restrict__ qimg, const float* __restrict__ simg,
    const u16* __restrict__ Wt, const float* __restrict__ bias,
    float* __restrict__ Z) {
  __shared__ __align__(16) u16 As[128 * BK];
  __shared__ __align__(16) u16 Bs[128 * BK];
  const int tid  = threadIdx.x;
  const int lane = tid & 63, wid = tid >> 6;
  const int wr = wid >> 1, wc = wid & 1;
  const int rowBase = blockIdx.x * 128;
  const int colBase = blockIdx.y * 128;

  // ---- A staging constants: 4 chunks of 16B (8 bf16 <- 8 f32) per thread ----
  const float* asrc[4];   // row pointer + swizzled column offset folded in
  int aw[4];              // u16 store index (linear = chunk*8)
#pragma unroll
  for (int i = 0; i < 4; ++i) {
    int g = i * 256 + tid;                    // 16B chunk id, 1024 total
    int row = g >> 3;
    int colb = ((g & 7) << 4) ^ ((row & 7) << 4);   // inverse swizzle (involution)
    int grow = rowBase + row;
    int sr = grow - N_QUERY; if (sr > N_SUP - 1) sr = N_SUP - 1;
    const float* base = (grow < N_QUERY) ? qimg + (size_t)grow * F_IN
                                         : simg + (size_t)sr * F_IN;
    asrc[i] = base + (colb >> 1);             // f32 col index = bf16 col index
    aw[i] = g * 8;
  }
  // ---- B staging constants: 4 gload_lds chunks per thread ----
  const u16* bsrc[4];
  unsigned bldsoff[4];                        // wave-uniform LDS byte base
#pragma unroll
  for (int i = 0; i < 4; ++i) {
    int g = i * 256 + tid;
    int n = g >> 3;
    int kb = ((g & 7) << 4) ^ ((n & 7) << 4);
    bsrc[i] = Wt + (size_t)(colBase + n) * F_IN + (kb >> 1);
    bldsoff[i] = i * 4096 + wid * 1024;
  }
  // ---- fragment read offsets (u16 index, ks=0); ks toggles bit5 ----
  int aoff[4], boff[4];
#pragma unroll
  for (int m = 0; m < 4; ++m) {
    int row = wr * 64 + m * 16 + (lane & 15);
    aoff[m] = (row * 128 + (((lane >> 4) << 4) ^ ((row & 7) << 4))) >> 1;
  }
#pragma unroll
  for (int n = 0; n < 4; ++n) {
    int row = wc * 64 + n * 16 + (lane & 15);
    boff[n] = (row * 128 + (((lane >> 4) << 4) ^ ((row & 7) << 4))) >> 1;
  }

  f32x4 acc[4][4] = {};

  for (int kt = 0; kt < F_IN / BK; ++kt) {
    // B: async global->LDS, 4 x dwordx4 per thread
#pragma unroll
    for (int i = 0; i < 4; ++i)
      __builtin_amdgcn_global_load_lds(GLB_PTR(bsrc[i] + kt * BK),
                                       LDS_PTR((char*)Bs + bldsoff[i]), 16, 0, 0);
    // A: f32 loads
    float4 v[4][2];
#pragma unroll
    for (int i = 0; i < 4; ++i) {
      const float* p = asrc[i] + kt * BK;
      v[i][0] = *(const float4*)(p);
      v[i][1] = *(const float4*)(p + 4);
    }
    // cvt + linear 16B ds_write
#pragma unroll
    for (int i = 0; i < 4; ++i) {
      u16x8 pk = { f2b(v[i][0].x), f2b(v[i][0].y), f2b(v[i][0].z), f2b(v[i][0].w),
                   f2b(v[i][1].x), f2b(v[i][1].y), f2b(v[i][1].z), f2b(v[i][1].w) };
      *(u16x8*)&As[aw[i]] = pk;
    }
    __syncthreads();   // drains vmcnt (gload_lds) + lgkm (ds_write)

#pragma unroll
    for (int ks = 0; ks < 2; ++ks) {
      bf16x8 a[4], b[4];
#pragma unroll
      for (int m = 0; m < 4; ++m) a[m] = *(const bf16x8*)&As[aoff[m] ^ (ks << 5)];
#pragma unroll
      for (int n = 0; n < 4; ++n) b[n] = *(const bf16x8*)&Bs[boff[n] ^ (ks << 5)];
#pragma unroll
      for (int m = 0; m < 4; ++m)
#pragma unroll
        for (int n = 0; n < 4; ++n)
          acc[m][n] = __builtin_amdgcn_mfma_f32_16x16x32_bf16(a[m], b[n], acc[m][n], 0, 0, 0);
    }
    __syncthreads();
  }

#pragma unroll
  for (int n = 0; n < 4; ++n) {
    int c = colBase + wc * 64 + n * 16 + (lane & 15);
    float bvv = bias[c];
#pragma unroll
    for (int m = 0; m < 4; ++m) {
      int r0 = rowBase + wr * 64 + m * 16 + ((lane >> 4) * 4);
#pragma unroll
      for (int r = 0; r < 4; ++r)
        Z[(size_t)(r0 + r) * D_EMB + c] = acc[m][n][r] + bvv;
    }
  }
}

// ---------------- prototypes: z_total [128][1024] (rows >=100 zeroed) -------
__global__ __launch_bounds__(256) void proto_k(const float* __restrict__ Z,
                                               float* __restrict__ Ztf) {
  int gid = blockIdx.x * 256 + threadIdx.x;   // 128*1024 threads
  int w = gid >> 10, d = gid & 1023;
  float outv = 0.f;
  if (w < N_WAY) {
    float v[10]; float s = 0.f;
#pragma unroll
    for (int k = 0; k < 10; ++k) {
      v[k] = Z[(size_t)(N_QUERY + w * 10 + k) * D_EMB + d];
      s += v[k];
    }
#pragma unroll
    for (int a = 0; a < 9; ++a)
#pragma unroll
      for (int b2 = 0; b2 < 9; ++b2)
        if (b2 < 9 - a) {
          float lo = fminf(v[b2], v[b2 + 1]);
          float hi = fmaxf(v[b2], v[b2 + 1]);
          v[b2] = lo; v[b2 + 1] = hi;
        }
    outv = 0.5f * (v[4] + s * 0.1f);   // lower median + mean, halved
  }
  Ztf[gid] = outv;
}

// ---------------- per-row stats + bf16 cast ---------------------------------
__global__ __launch_bounds__(256) void stats_k(const float* __restrict__ in,
                                               u16* __restrict__ outb,
                                               float* __restrict__ sum2,
                                               float* __restrict__ sum1) {
  int row = blockIdx.x;
  const float* r = in + (size_t)row * D_EMB;
  int t = threadIdx.x;
  float4 v = *(const float4*)(r + t * 4);
  u16x4 u4 = { f2b(v.x), f2b(v.y), f2b(v.z), f2b(v.w) };
  *(u16x4*)(outb + (size_t)row * D_EMB + t * 4) = u4;
  float s  = v.x + v.y + v.z + v.w;
  float s2 = v.x * v.x + v.y * v.y + v.z * v.z + v.w * v.w;
#pragma unroll
  for (int off = 32; off > 0; off >>= 1) {
    s  += __shfl_down(s, off);
    s2 += __shfl_down(s2, off);
  }
  __shared__ float as1[4], as2[4];
  if ((t & 63) == 0) { as1[t >> 6] = s; as2[t >> 6] = s2; }
  __syncthreads();
  if (t == 0) {
    sum1[row] = as1[0] + as1[1] + as1[2] + as1[3];
    sum2[row] = as2[0] + as2[1] + as2[2] + as2[3];
  }
}

// ---------------- GEMM2: cross + fused distance -----------------------------
// out[q][p] = -sqrt(max(q2+p2-2*cross+2e-6*(qs-ps)+D*1e-12, 0))
#define LDA2 40
__global__ __launch_bounds__(256) void gemm2_k(
    const u16* __restrict__ Zq, const u16* __restrict__ Ztb,
    const float* __restrict__ q2, const float* __restrict__ qs,
    const float* __restrict__ p2, const float* __restrict__ ps,
    float* __restrict__ out) {
  __shared__ u16 As[64][LDA2];
  __shared__ u16 Bs[128][LDA2];
  const int tid = threadIdx.x;
  const int lane = tid & 63, wid = tid >> 6;
  const int wr = wid >> 1, wc = wid & 1;
  const int rowBase = blockIdx.x * 64;

  f32x4 acc[2][4] = {};

  for (int kt = 0; kt < D_EMB / 32; ++kt) {
    u16x8 avv;
    {
      int row = tid >> 2, kh = tid & 3;
      avv = *(const u16x8*)(Zq + (size_t)(rowBase + row) * D_EMB + kt * 32 + kh * 8);
    }
    u16x8 bvv[2];
#pragma unroll
    for (int i = 0; i < 2; ++i) {
      int u = i * 256 + tid;
      int n = u >> 2, kh = u & 3;
      bvv[i] = *(const u16x8*)(Ztb + (size_t)n * D_EMB + kt * 32 + kh * 8);
    }
    __syncthreads();
    {
      int row = tid >> 2, kh = tid & 3;
      *(u16x8*)&As[row][kh * 8] = avv;
    }
#pragma unroll
    for (int i = 0; i < 2; ++i) {
      int u = i * 256 + tid;
      int n = u >> 2, kh = u & 3;
      *(u16x8*)&Bs[n][kh * 8] = bvv[i];
    }
    __syncthreads();

    bf16x8 a[2], b[4];
#pragma unroll
    for (int m = 0; m < 2; ++m)
      a[m] = *(const bf16x8*)&As[wr * 32 + m * 16 + (lane & 15)][(lane >> 4) * 8];
#pragma unroll
    for (int n = 0; n < 4; ++n)
      b[n] = *(const bf16x8*)&Bs[wc * 64 + n * 16 + (lane & 15)][(lane >> 4) * 8];
#pragma unroll
    for (int m = 0; m < 2; ++m)
#pragma unroll
      for (int n = 0; n < 4; ++n)
        acc[m][n] = __builtin_amdgcn_mfma_f32_16x16x32_bf16(a[m], b[n], acc[m][n], 0, 0, 0);
    __syncthreads();
  }

#pragma unroll
  for (int m = 0; m < 2; ++m) {
    int r0 = rowBase + wr * 32 + m * 16 + ((lane >> 4) * 4);
    float q2v[4], qsv[4];
#pragma unroll
    for (int r = 0; r < 4; ++r) { q2v[r] = q2[r0 + r]; qsv[r] = qs[r0 + r]; }
#pragma unroll
    for (int n = 0; n < 4; ++n) {
      int c = wc * 64 + n * 16 + (lane & 15);
      if (c < N_WAY) {
        float pp = p2[c], pss = ps[c];
#pragma unroll
        for (int r = 0; r < 4; ++r) {
          float sq = q2v[r] + pp - 2.f * acc[m][n][r]
                   + 2e-6f * (qsv[r] - pss) + (float)D_EMB * 1e-12f;
          out[(size_t)(r0 + r) * N_WAY + c] = -sqrtf(fmaxf(sq, 0.f));
        }
      }
    }
  }
}

// ---------------- launch -----------------------------------------------------
extern "C" void kernel_launch(void* const* d_in, const int* in_sizes, int n_in,
                              void* d_out, int out_size, void* d_ws, size_t ws_size,
                              hipStream_t stream) {
  const float* simg = (const float*)d_in[0];
  // d_in[1] = support_labels: labels = i/10 already sorted -> identity argsort
  const float* qimg = (const float*)d_in[2];
  const float* W    = (const float*)d_in[3];
  const float* bias = (const float*)d_in[4];
  float* out = (float*)d_out;

  char* ws = (char*)d_ws;
  u16*   Wt  = (u16*)(ws);                 //  8,388,608 B
  float* Z   = (float*)(ws + 8388608);     // 37,748,736 B
  u16*   Zq  = (u16*)(ws + 46137344);      // 16,777,216 B
  float* Ztf = (float*)(ws + 62914560);    //    524,288 B
  u16*   Ztb = (u16*)(ws + 63438848);      //    262,144 B
  float* q2  = (float*)(ws + 63700992);    //     32,768 B
  float* qs  = (float*)(ws + 63733760);    //     32,768 B
  float* p2  = (float*)(ws + 63766528);    //        512 B
  float* ps  = (float*)(ws + 63767040);    //        512 B

  hipLaunchKernelGGL(wt_k,    dim3(128, 32), dim3(256), 0, stream, W, Wt);
  hipLaunchKernelGGL(gemm1_k, dim3(72, 8),   dim3(256), 0, stream, qimg, simg, Wt, bias, Z);
  hipLaunchKernelGGL(proto_k, dim3(512),     dim3(256), 0, stream, Z, Ztf);
  hipLaunchKernelGGL(stats_k, dim3(8192),    dim3(256), 0, stream, Z, Zq, q2, qs);
  hipLaunchKernelGGL(stats_k, dim3(128),     dim3(256), 0, stream, Ztf, Ztb, p2, ps);
  hipLaunchKernelGGL(gemm2_k, dim3(128),     dim3(256), 0, stream, Zq, Ztb, q2, qs, p2, ps, out);
}

// Round 3
// 205.764 us; speedup vs baseline: 1.1079x; 1.1079x over previous
//
#include <hip/hip_runtime.h>

// PrototypicalNetworkModel on MI355X.
// Pipeline: W^T->bf16 transpose | bf16-MFMA GEMM (query+support stacked,
// 64x128 tile, gload_lds B + reg-staged cvt A, T2 XOR-swizzled LDS, BK=64) |
// prototype median+mean | per-row stats + bf16 cast | cross-GEMM with fused
// sqrt-distance epilogue.

typedef unsigned short u16;
typedef __attribute__((ext_vector_type(4))) unsigned short u16x4;
typedef __attribute__((ext_vector_type(8))) unsigned short u16x8;
typedef __attribute__((ext_vector_type(8))) short bf16x8;   // 8 bf16 (4 VGPRs)
typedef __attribute__((ext_vector_type(4))) float f32x4;

#define N_QUERY 8192
#define F_IN    4096
#define D_EMB   1024
#define N_SUP   1000
#define N_WAY   100
#define BK      64

__device__ __forceinline__ u16 f2b(float f) {   // f32 -> bf16 RNE
  unsigned int u = __builtin_bit_cast(unsigned int, f);
  u += 0x7FFFu + ((u >> 16) & 1u);
  return (u16)(u >> 16);
}

#define GLB_PTR(p) ((const __attribute__((address_space(1))) unsigned int*)(p))
#define LDS_PTR(p) ((__attribute__((address_space(3))) unsigned int*)(p))

// ---------------- W [4096][1024] f32 -> Wt [1024][4096] bf16 ----------------
__global__ __launch_bounds__(256) void wt_k(const float* __restrict__ W,
                                            u16* __restrict__ Wt) {
  __shared__ float tile[32][33];
  int kb = blockIdx.x * 32, nb = blockIdx.y * 32;
  int tx = threadIdx.x & 31, ty = threadIdx.x >> 5;
#pragma unroll
  for (int i = 0; i < 4; ++i) {
    int k = ty + i * 8;
    tile[k][tx] = W[(size_t)(kb + k) * D_EMB + nb + tx];
  }
  __syncthreads();
#pragma unroll
  for (int i = 0; i < 4; ++i) {
    int n = ty + i * 8;
    Wt[(size_t)(nb + n) * F_IN + kb + tx] = f2b(tile[tx][n]);
  }
}

// ---------------- GEMM1: Z[9216][1024] = A[9216][4096] @ W + b -------------
// 64x128 tile, 4 waves as 2x2 (each wave 32x64 output).
// LDS rows are 64 bf16 = 128B, T2 storage swizzle:
//   storage_byte = row*128 + (col_byte ^ ((row&7)<<4))
// B staged via global_load_lds (linear dest, inverse-swizzled global source).
// A (f32) reg-staged: load -> f2b -> linear ds_write_b128 of swizzled chunks.
__global__ __launch_bounds__(256) void gemm1_k(
    const float* __restrict__ qimg, const float* __restrict__ simg,
    const u16* __restrict__ Wt, const float* __restrict__ bias,
    float* __restrict__ Z) {
  __shared__ __align__(16) u16 As[64 * BK];     //  8 KB
  __shared__ __align__(16) u16 Bs[128 * BK];    // 16 KB
  const int tid  = threadIdx.x;
  const int lane = tid & 63, wid = tid >> 6;
  const int wr = wid >> 1, wc = wid & 1;
  const int rowBase = blockIdx.x * 64;
  const int colBase = blockIdx.y * 128;

  // ---- A staging: 2 chunks of 16B (8 bf16 <- 8 f32) per thread ----
  const float* asrc[2];
  int aw[2];
#pragma unroll
  for (int i = 0; i < 2; ++i) {
    int g = i * 256 + tid;                    // chunk id, 512 total (64 rows x 8)
    int row = g >> 3;
    int colb = ((g & 7) << 4) ^ ((row & 7) << 4);   // inverse swizzle (involution)
    int grow = rowBase + row;
    int sr = grow - N_QUERY; if (sr < 0) sr = 0; if (sr > N_SUP - 1) sr = N_SUP - 1;
    const float* base = (grow < N_QUERY) ? qimg + (size_t)grow * F_IN
                                         : simg + (size_t)sr * F_IN;
    asrc[i] = base + (colb >> 1);
    aw[i] = g * 8;
  }
  // ---- B staging: 4 gload_lds chunks per thread ----
  const u16* bsrc[4];
  unsigned bldsoff[4];                        // wave-uniform LDS byte base
#pragma unroll
  for (int i = 0; i < 4; ++i) {
    int g = i * 256 + tid;                    // 1024 chunks (128 rows x 8)
    int n = g >> 3;
    int kb = ((g & 7) << 4) ^ ((n & 7) << 4);
    bsrc[i] = Wt + (size_t)(colBase + n) * F_IN + (kb >> 1);
    bldsoff[i] = i * 4096 + wid * 1024;
  }
  // ---- fragment read offsets (u16 index, ks=0); ks toggles bit5 ----
  int aoff[2], boff[4];
#pragma unroll
  for (int m = 0; m < 2; ++m) {
    int row = wr * 32 + m * 16 + (lane & 15);
    aoff[m] = (row * 128 + (((lane >> 4) << 4) ^ ((row & 7) << 4))) >> 1;
  }
#pragma unroll
  for (int n = 0; n < 4; ++n) {
    int row = wc * 64 + n * 16 + (lane & 15);
    boff[n] = (row * 128 + (((lane >> 4) << 4) ^ ((row & 7) << 4))) >> 1;
  }

  f32x4 acc[2][4] = {};

  for (int kt = 0; kt < F_IN / BK; ++kt) {
    // B: async global->LDS, 4 x dwordx4 per thread
#pragma unroll
    for (int i = 0; i < 4; ++i)
      __builtin_amdgcn_global_load_lds(GLB_PTR(bsrc[i] + kt * BK),
                                       LDS_PTR((char*)Bs + bldsoff[i]), 16, 0, 0);
    // A: f32 loads -> cvt -> linear 16B ds_write
#pragma unroll
    for (int i = 0; i < 2; ++i) {
      const float* p = asrc[i] + kt * BK;
      float4 v0 = *(const float4*)(p);
      float4 v1 = *(const float4*)(p + 4);
      u16x8 pk = { f2b(v0.x), f2b(v0.y), f2b(v0.z), f2b(v0.w),
                   f2b(v1.x), f2b(v1.y), f2b(v1.z), f2b(v1.w) };
      *(u16x8*)&As[aw[i]] = pk;
    }
    __syncthreads();   // drains vmcnt (gload_lds) + lgkm (ds_write)

#pragma unroll
    for (int ks = 0; ks < 2; ++ks) {
      bf16x8 a[2], b[4];
#pragma unroll
      for (int m = 0; m < 2; ++m) a[m] = *(const bf16x8*)&As[aoff[m] ^ (ks << 5)];
#pragma unroll
      for (int n = 0; n < 4; ++n) b[n] = *(const bf16x8*)&Bs[boff[n] ^ (ks << 5)];
#pragma unroll
      for (int m = 0; m < 2; ++m)
#pragma unroll
        for (int n = 0; n < 4; ++n)
          acc[m][n] = __builtin_amdgcn_mfma_f32_16x16x32_bf16(a[m], b[n], acc[m][n], 0, 0, 0);
    }
    __syncthreads();
  }

#pragma unroll
  for (int n = 0; n < 4; ++n) {
    int c = colBase + wc * 64 + n * 16 + (lane & 15);
    float bvv = bias[c];
#pragma unroll
    for (int m = 0; m < 2; ++m) {
      int r0 = rowBase + wr * 32 + m * 16 + ((lane >> 4) * 4);
#pragma unroll
      for (int r = 0; r < 4; ++r)
        Z[(size_t)(r0 + r) * D_EMB + c] = acc[m][n][r] + bvv;
    }
  }
}

// ---------------- prototypes: z_total [128][1024] (rows >=100 zeroed) -------
__global__ __launch_bounds__(256) void proto_k(const float* __restrict__ Z,
                                               float* __restrict__ Ztf) {
  int gid = blockIdx.x * 256 + threadIdx.x;   // 128*1024 threads
  int w = gid >> 10, d = gid & 1023;
  float outv = 0.f;
  if (w < N_WAY) {
    float v[10]; float s = 0.f;
#pragma unroll
    for (int k = 0; k < 10; ++k) {
      v[k] = Z[(size_t)(N_QUERY + w * 10 + k) * D_EMB + d];
      s += v[k];
    }
#pragma unroll
    for (int a = 0; a < 9; ++a)
#pragma unroll
      for (int b2 = 0; b2 < 9; ++b2)
        if (b2 < 9 - a) {
          float lo = fminf(v[b2], v[b2 + 1]);
          float hi = fmaxf(v[b2], v[b2 + 1]);
          v[b2] = lo; v[b2 + 1] = hi;
        }
    outv = 0.5f * (v[4] + s * 0.1f);   // lower median + mean, halved
  }
  Ztf[gid] = outv;
}

// ---------------- per-row stats + bf16 cast ---------------------------------
__global__ __launch_bounds__(256) void stats_k(const float* __restrict__ in,
                                               u16* __restrict__ outb,
                                               float* __restrict__ sum2,
                                               float* __restrict__ sum1) {
  int row = blockIdx.x;
  const float* r = in + (size_t)row * D_EMB;
  int t = threadIdx.x;
  float4 v = *(const float4*)(r + t * 4);
  u16x4 u4 = { f2b(v.x), f2b(v.y), f2b(v.z), f2b(v.w) };
  *(u16x4*)(outb + (size_t)row * D_EMB + t * 4) = u4;
  float s  = v.x + v.y + v.z + v.w;
  float s2 = v.x * v.x + v.y * v.y + v.z * v.z + v.w * v.w;
#pragma unroll
  for (int off = 32; off > 0; off >>= 1) {
    s  += __shfl_down(s, off);
    s2 += __shfl_down(s2, off);
  }
  __shared__ float as1[4], as2[4];
  if ((t & 63) == 0) { as1[t >> 6] = s; as2[t >> 6] = s2; }
  __syncthreads();
  if (t == 0) {
    sum1[row] = as1[0] + as1[1] + as1[2] + as1[3];
    sum2[row] = as2[0] + as2[1] + as2[2] + as2[3];
  }
}

// ---------------- GEMM2: cross + fused distance -----------------------------
// out[q][p] = -sqrt(max(q2+p2-2*cross+2e-6*(qs-ps)+D*1e-12, 0))
#define LDA2 40
__global__ __launch_bounds__(256) void gemm2_k(
    const u16* __restrict__ Zq, const u16* __restrict__ Ztb,
    const float* __restrict__ q2, const float* __restrict__ qs,
    const float* __restrict__ p2, const float* __restrict__ ps,
    float* __restrict__ out) {
  __shared__ u16 As[64][LDA2];
  __shared__ u16 Bs[128][LDA2];
  const int tid = threadIdx.x;
  const int lane = tid & 63, wid = tid >> 6;
  const int wr = wid >> 1, wc = wid & 1;
  const int rowBase = blockIdx.x * 64;

  f32x4 acc[2][4] = {};

  for (int kt = 0; kt < D_EMB / 32; ++kt) {
    u16x8 avv;
    {
      int row = tid >> 2, kh = tid & 3;
      avv = *(const u16x8*)(Zq + (size_t)(rowBase + row) * D_EMB + kt * 32 + kh * 8);
    }
    u16x8 bvv[2];
#pragma unroll
    for (int i = 0; i < 2; ++i) {
      int u = i * 256 + tid;
      int n = u >> 2, kh = u & 3;
      bvv[i] = *(const u16x8*)(Ztb + (size_t)n * D_EMB + kt * 32 + kh * 8);
    }
    __syncthreads();
    {
      int row = tid >> 2, kh = tid & 3;
      *(u16x8*)&As[row][kh * 8] = avv;
    }
#pragma unroll
    for (int i = 0; i < 2; ++i) {
      int u = i * 256 + tid;
      int n = u >> 2, kh = u & 3;
      *(u16x8*)&Bs[n][kh * 8] = bvv[i];
    }
    __syncthreads();

    bf16x8 a[2], b[4];
#pragma unroll
    for (int m = 0; m < 2; ++m)
      a[m] = *(const bf16x8*)&As[wr * 32 + m * 16 + (lane & 15)][(lane >> 4) * 8];
#pragma unroll
    for (int n = 0; n < 4; ++n)
      b[n] = *(const bf16x8*)&Bs[wc * 64 + n * 16 + (lane & 15)][(lane >> 4) * 8];
#pragma unroll
    for (int m = 0; m < 2; ++m)
#pragma unroll
      for (int n = 0; n < 4; ++n)
        acc[m][n] = __builtin_amdgcn_mfma_f32_16x16x32_bf16(a[m], b[n], acc[m][n], 0, 0, 0);
    __syncthreads();
  }

#pragma unroll
  for (int m = 0; m < 2; ++m) {
    int r0 = rowBase + wr * 32 + m * 16 + ((lane >> 4) * 4);
    float q2v[4], qsv[4];
#pragma unroll
    for (int r = 0; r < 4; ++r) { q2v[r] = q2[r0 + r]; qsv[r] = qs[r0 + r]; }
#pragma unroll
    for (int n = 0; n < 4; ++n) {
      int c = wc * 64 + n * 16 + (lane & 15);
      if (c < N_WAY) {
        float pp = p2[c], pss = ps[c];
#pragma unroll
        for (int r = 0; r < 4; ++r) {
          float sq = q2v[r] + pp - 2.f * acc[m][n][r]
                   + 2e-6f * (qsv[r] - pss) + (float)D_EMB * 1e-12f;
          out[(size_t)(r0 + r) * N_WAY + c] = -sqrtf(fmaxf(sq, 0.f));
        }
      }
    }
  }
}

// ---------------- launch -----------------------------------------------------
extern "C" void kernel_launch(void* const* d_in, const int* in_sizes, int n_in,
                              void* d_out, int out_size, void* d_ws, size_t ws_size,
                              hipStream_t stream) {
  const float* simg = (const float*)d_in[0];
  // d_in[1] = support_labels: labels = i/10 already sorted -> identity argsort
  const float* qimg = (const float*)d_in[2];
  const float* W    = (const float*)d_in[3];
  const float* bias = (const float*)d_in[4];
  float* out = (float*)d_out;

  char* ws = (char*)d_ws;
  u16*   Wt  = (u16*)(ws);                 //  8,388,608 B
  float* Z   = (float*)(ws + 8388608);     // 37,748,736 B
  u16*   Zq  = (u16*)(ws + 46137344);      // 16,777,216 B
  float* Ztf = (float*)(ws + 62914560);    //    524,288 B
  u16*   Ztb = (u16*)(ws + 63438848);      //    262,144 B
  float* q2  = (float*)(ws + 63700992);    //     32,768 B
  float* qs  = (float*)(ws + 63733760);    //     32,768 B
  float* p2  = (float*)(ws + 63766528);    //        512 B
  float* ps  = (float*)(ws + 63767040);    //        512 B

  hipLaunchKernelGGL(wt_k,    dim3(128, 32), dim3(256), 0, stream, W, Wt);
  hipLaunchKernelGGL(gemm1_k, dim3(144, 8),  dim3(256), 0, stream, qimg, simg, Wt, bias, Z);
  hipLaunchKernelGGL(proto_k, dim3(512),     dim3(256), 0, stream, Z, Ztf);
  hipLaunchKernelGGL(stats_k, dim3(8192),    dim3(256), 0, stream, Z, Zq, q2, qs);
  hipLaunchKernelGGL(stats_k, dim3(128),     dim3(256), 0, stream, Ztf, Ztb, p2, ps);
  hipLaunchKernelGGL(gemm2_k, dim3(128),     dim3(256), 0, stream, Zq, Ztb, q2, qs, p2, ps, out);
}

// Round 4
// 188.747 us; speedup vs baseline: 1.2078x; 1.0902x over previous
//
#include <hip/hip_runtime.h>

// PrototypicalNetworkModel on MI355X.
// Pipeline: W^T->bf16 transpose | bf16-MFMA GEMM (query+support stacked,
// 64x128 tile, 2-phase double-buffered LDS: gload_lds B + reg-staged cvt A,
// T2 XOR-swizzled LDS, BK=64, XCD-aware col-fastest block swizzle) |
// prototype median+mean | per-row stats + bf16 cast | cross-GEMM with fused
// sqrt-distance epilogue.

typedef unsigned short u16;
typedef __attribute__((ext_vector_type(4))) unsigned short u16x4;
typedef __attribute__((ext_vector_type(8))) unsigned short u16x8;
typedef __attribute__((ext_vector_type(8))) short bf16x8;   // 8 bf16 (4 VGPRs)
typedef __attribute__((ext_vector_type(4))) float f32x4;

#define N_QUERY 8192
#define F_IN    4096
#define D_EMB   1024
#define N_SUP   1000
#define N_WAY   100
#define BK      64

__device__ __forceinline__ u16 f2b(float f) {   // f32 -> bf16 RNE
  unsigned int u = __builtin_bit_cast(unsigned int, f);
  u += 0x7FFFu + ((u >> 16) & 1u);
  return (u16)(u >> 16);
}

#define GLB_PTR(p) ((const __attribute__((address_space(1))) unsigned int*)(p))
#define LDS_PTR(p) ((__attribute__((address_space(3))) unsigned int*)(p))

// ---------------- W [4096][1024] f32 -> Wt [1024][4096] bf16 ----------------
__global__ __launch_bounds__(256) void wt_k(const float* __restrict__ W,
                                            u16* __restrict__ Wt) {
  __shared__ float tile[32][33];
  int kb = blockIdx.x * 32, nb = blockIdx.y * 32;
  int tx = threadIdx.x & 31, ty = threadIdx.x >> 5;
#pragma unroll
  for (int i = 0; i < 4; ++i) {
    int k = ty + i * 8;
    tile[k][tx] = W[(size_t)(kb + k) * D_EMB + nb + tx];
  }
  __syncthreads();
#pragma unroll
  for (int i = 0; i < 4; ++i) {
    int n = ty + i * 8;
    Wt[(size_t)(nb + n) * F_IN + kb + tx] = f2b(tile[tx][n]);
  }
}

// ---------------- GEMM1: Z[9216][1024] = A[9216][4096] @ W + b -------------
// 64x128 tile, 4 waves as 2x2 (each wave 32x64 output), double-buffered LDS.
// LDS rows are 64 bf16 = 128B, T2 storage swizzle:
//   storage_byte = row*128 + (col_byte ^ ((row&7)<<4))
// B staged via global_load_lds (linear dest, inverse-swizzled global source).
// A (f32) reg-staged: issue loads early, f2b + linear ds_write after MFMA.
// One __syncthreads per K-step (2-phase schedule).
__global__ __launch_bounds__(256) void gemm1_k(
    const float* __restrict__ qimg, const float* __restrict__ simg,
    const u16* __restrict__ Wt, const float* __restrict__ bias,
    float* __restrict__ Z) {
  __shared__ __align__(16) u16 As0[64 * BK],  As1[64 * BK];    // 8 KB each
  __shared__ __align__(16) u16 Bs0[128 * BK], Bs1[128 * BK];   // 16 KB each
  const int tid  = threadIdx.x;
  const int lane = tid & 63, wid = tid >> 6;
  const int wr = wid >> 1, wc = wid & 1;
  // XCD-aware swizzle: grid is (8 cols, 144 rows); 1152 % 8 == 0 -> simple form.
  // Each XCD gets 18 consecutive row-panels x all 8 cols (col fastest) -> the
  // 8 blocks sharing an A row-panel are temporally adjacent on one XCD's L2.
  int lin = blockIdx.x + (blockIdx.y << 3);
  int swz = (lin & 7) * 144 + (lin >> 3);
  const int rowBase = (swz >> 3) * 64;
  const int colBase = (swz & 7) * 128;

  // ---- A staging: 2 chunks of 16B (8 bf16 <- 8 f32) per thread ----
  const float* asrc[2];
  int aw[2];
#pragma unroll
  for (int i = 0; i < 2; ++i) {
    int g = i * 256 + tid;                    // chunk id, 512 total (64 rows x 8)
    int row = g >> 3;
    int colb = ((g & 7) << 4) ^ ((row & 7) << 4);   // inverse swizzle (involution)
    int grow = rowBase + row;
    int sr = grow - N_QUERY; if (sr < 0) sr = 0; if (sr > N_SUP - 1) sr = N_SUP - 1;
    const float* base = (grow < N_QUERY) ? qimg + (size_t)grow * F_IN
                                         : simg + (size_t)sr * F_IN;
    asrc[i] = base + (colb >> 1);
    aw[i] = g * 8;
  }
  // ---- B staging: 4 gload_lds chunks per thread ----
  const u16* bsrc[4];
  unsigned bldsoff[4];                        // wave-uniform LDS byte base
#pragma unroll
  for (int i = 0; i < 4; ++i) {
    int g = i * 256 + tid;                    // 1024 chunks (128 rows x 8)
    int n = g >> 3;
    int kb = ((g & 7) << 4) ^ ((n & 7) << 4);
    bsrc[i] = Wt + (size_t)(colBase + n) * F_IN + (kb >> 1);
    bldsoff[i] = i * 4096 + wid * 1024;
  }
  // ---- fragment read offsets (u16 index, ks=0); ks toggles bit5 ----
  int aoff[2], boff[4];
#pragma unroll
  for (int m = 0; m < 2; ++m) {
    int row = wr * 32 + m * 16 + (lane & 15);
    aoff[m] = (row * 128 + (((lane >> 4) << 4) ^ ((row & 7) << 4))) >> 1;
  }
#pragma unroll
  for (int n = 0; n < 4; ++n) {
    int row = wc * 64 + n * 16 + (lane & 15);
    boff[n] = (row * 128 + (((lane >> 4) << 4) ^ ((row & 7) << 4))) >> 1;
  }

  f32x4 acc[2][4] = {};

// One K-step: issue STAGE(KTN)->NXT buffers, compute CUR buffers, write A
// after MFMA (T14 issue-early/write-late), single barrier.
#define STEP(CURA, CURB, NXTA, NXTB, KTN, DOSTAGE)                             \
  {                                                                            \
    float4 v00 = {}, v01 = {}, v10 = {}, v11 = {};                             \
    if (DOSTAGE) {                                                             \
      _Pragma("unroll")                                                        \
      for (int i = 0; i < 4; ++i)                                              \
        __builtin_amdgcn_global_load_lds(GLB_PTR(bsrc[i] + (KTN) * BK),        \
            LDS_PTR((char*)(NXTB) + bldsoff[i]), 16, 0, 0);                    \
      const float* p0 = asrc[0] + (KTN) * BK;                                  \
      const float* p1 = asrc[1] + (KTN) * BK;                                  \
      v00 = *(const float4*)p0; v01 = *(const float4*)(p0 + 4);                \
      v10 = *(const float4*)p1; v11 = *(const float4*)(p1 + 4);                \
    }                                                                          \
    _Pragma("unroll")                                                          \
    for (int ks = 0; ks < 2; ++ks) {                                           \
      bf16x8 a[2], b[4];                                                       \
      _Pragma("unroll")                                                        \
      for (int m = 0; m < 2; ++m)                                              \
        a[m] = *(const bf16x8*)&(CURA)[aoff[m] ^ (ks << 5)];                   \
      _Pragma("unroll")                                                        \
      for (int n = 0; n < 4; ++n)                                              \
        b[n] = *(const bf16x8*)&(CURB)[boff[n] ^ (ks << 5)];                   \
      _Pragma("unroll")                                                        \
      for (int m = 0; m < 2; ++m)                                              \
        _Pragma("unroll")                                                      \
        for (int n = 0; n < 4; ++n)                                            \
          acc[m][n] = __builtin_amdgcn_mfma_f32_16x16x32_bf16(a[m], b[n],      \
                                                              acc[m][n], 0, 0, 0); \
    }                                                                          \
    if (DOSTAGE) {                                                             \
      u16x8 pk0 = { f2b(v00.x), f2b(v00.y), f2b(v00.z), f2b(v00.w),            \
                    f2b(v01.x), f2b(v01.y), f2b(v01.z), f2b(v01.w) };          \
      u16x8 pk1 = { f2b(v10.x), f2b(v10.y), f2b(v10.z), f2b(v10.w),            \
                    f2b(v11.x), f2b(v11.y), f2b(v11.z), f2b(v11.w) };          \
      *(u16x8*)&(NXTA)[aw[0]] = pk0;                                           \
      *(u16x8*)&(NXTA)[aw[1]] = pk1;                                           \
    }                                                                          \
    __syncthreads();                                                           \
  }

  // prologue: stage kt=0 into buf0
#pragma unroll
  for (int i = 0; i < 4; ++i)
    __builtin_amdgcn_global_load_lds(GLB_PTR(bsrc[i]),
        LDS_PTR((char*)Bs0 + bldsoff[i]), 16, 0, 0);
  {
    const float* p0 = asrc[0];
    const float* p1 = asrc[1];
    float4 v00 = *(const float4*)p0, v01 = *(const float4*)(p0 + 4);
    float4 v10 = *(const float4*)p1, v11 = *(const float4*)(p1 + 4);
    u16x8 pk0 = { f2b(v00.x), f2b(v00.y), f2b(v00.z), f2b(v00.w),
                  f2b(v01.x), f2b(v01.y), f2b(v01.z), f2b(v01.w) };
    u16x8 pk1 = { f2b(v10.x), f2b(v10.y), f2b(v10.z), f2b(v10.w),
                  f2b(v11.x), f2b(v11.y), f2b(v11.z), f2b(v11.w) };
    *(u16x8*)&As0[aw[0]] = pk0;
    *(u16x8*)&As0[aw[1]] = pk1;
  }
  __syncthreads();

#pragma unroll 1
  for (int t2 = 0; t2 < 31; ++t2) {
    STEP(As0, Bs0, As1, Bs1, 2 * t2 + 1, true);
    STEP(As1, Bs1, As0, Bs0, 2 * t2 + 2, true);
  }
  STEP(As0, Bs0, As1, Bs1, 63, true);    // compute kt=62, stage kt=63
  STEP(As1, Bs1, As0, Bs0, 0,  false);   // compute kt=63
#undef STEP

#pragma unroll
  for (int n = 0; n < 4; ++n) {
    int c = colBase + wc * 64 + n * 16 + (lane & 15);
    float bvv = bias[c];
#pragma unroll
    for (int m = 0; m < 2; ++m) {
      int r0 = rowBase + wr * 32 + m * 16 + ((lane >> 4) * 4);
#pragma unroll
      for (int r = 0; r < 4; ++r)
        Z[(size_t)(r0 + r) * D_EMB + c] = acc[m][n][r] + bvv;
    }
  }
}

// ---------------- prototypes: z_total [128][1024] (rows >=100 zeroed) -------
__global__ __launch_bounds__(256) void proto_k(const float* __restrict__ Z,
                                               float* __restrict__ Ztf) {
  int gid = blockIdx.x * 256 + threadIdx.x;   // 128*1024 threads
  int w = gid >> 10, d = gid & 1023;
  float outv = 0.f;
  if (w < N_WAY) {
    float v[10]; float s = 0.f;
#pragma unroll
    for (int k = 0; k < 10; ++k) {
      v[k] = Z[(size_t)(N_QUERY + w * 10 + k) * D_EMB + d];
      s += v[k];
    }
#pragma unroll
    for (int a = 0; a < 9; ++a)
#pragma unroll
      for (int b2 = 0; b2 < 9; ++b2)
        if (b2 < 9 - a) {
          float lo = fminf(v[b2], v[b2 + 1]);
          float hi = fmaxf(v[b2], v[b2 + 1]);
          v[b2] = lo; v[b2 + 1] = hi;
        }
    outv = 0.5f * (v[4] + s * 0.1f);   // lower median + mean, halved
  }
  Ztf[gid] = outv;
}

// ---------------- per-row stats + bf16 cast ---------------------------------
__global__ __launch_bounds__(256) void stats_k(const float* __restrict__ in,
                                               u16* __restrict__ outb,
                                               float* __restrict__ sum2,
                                               float* __restrict__ sum1) {
  int row = blockIdx.x;
  const float* r = in + (size_t)row * D_EMB;
  int t = threadIdx.x;
  float4 v = *(const float4*)(r + t * 4);
  u16x4 u4 = { f2b(v.x), f2b(v.y), f2b(v.z), f2b(v.w) };
  *(u16x4*)(outb + (size_t)row * D_EMB + t * 4) = u4;
  float s  = v.x + v.y + v.z + v.w;
  float s2 = v.x * v.x + v.y * v.y + v.z * v.z + v.w * v.w;
#pragma unroll
  for (int off = 32; off > 0; off >>= 1) {
    s  += __shfl_down(s, off);
    s2 += __shfl_down(s2, off);
  }
  __shared__ float as1[4], as2[4];
  if ((t & 63) == 0) { as1[t >> 6] = s; as2[t >> 6] = s2; }
  __syncthreads();
  if (t == 0) {
    sum1[row] = as1[0] + as1[1] + as1[2] + as1[3];
    sum2[row] = as2[0] + as2[1] + as2[2] + as2[3];
  }
}

// ---------------- GEMM2: cross + fused distance -----------------------------
// out[q][p] = -sqrt(max(q2+p2-2*cross+2e-6*(qs-ps)+D*1e-12, 0))
#define LDA2 40
__global__ __launch_bounds__(256) void gemm2_k(
    const u16* __restrict__ Zq, const u16* __restrict__ Ztb,
    const float* __restrict__ q2, const float* __restrict__ qs,
    const float* __restrict__ p2, const float* __restrict__ ps,
    float* __restrict__ out) {
  __shared__ u16 As[64][LDA2];
  __shared__ u16 Bs[128][LDA2];
  const int tid = threadIdx.x;
  const int lane = tid & 63, wid = tid >> 6;
  const int wr = wid >> 1, wc = wid & 1;
  const int rowBase = blockIdx.x * 64;

  f32x4 acc[2][4] = {};

  for (int kt = 0; kt < D_EMB / 32; ++kt) {
    u16x8 avv;
    {
      int row = tid >> 2, kh = tid & 3;
      avv = *(const u16x8*)(Zq + (size_t)(rowBase + row) * D_EMB + kt * 32 + kh * 8);
    }
    u16x8 bvv[2];
#pragma unroll
    for (int i = 0; i < 2; ++i) {
      int u = i * 256 + tid;
      int n = u >> 2, kh = u & 3;
      bvv[i] = *(const u16x8*)(Ztb + (size_t)n * D_EMB + kt * 32 + kh * 8);
    }
    __syncthreads();
    {
      int row = tid >> 2, kh = tid & 3;
      *(u16x8*)&As[row][kh * 8] = avv;
    }
#pragma unroll
    for (int i = 0; i < 2; ++i) {
      int u = i * 256 + tid;
      int n = u >> 2, kh = u & 3;
      *(u16x8*)&Bs[n][kh * 8] = bvv[i];
    }
    __syncthreads();

    bf16x8 a[2], b[4];
#pragma unroll
    for (int m = 0; m < 2; ++m)
      a[m] = *(const bf16x8*)&As[wr * 32 + m * 16 + (lane & 15)][(lane >> 4) * 8];
#pragma unroll
    for (int n = 0; n < 4; ++n)
      b[n] = *(const bf16x8*)&Bs[wc * 64 + n * 16 + (lane & 15)][(lane >> 4) * 8];
#pragma unroll
    for (int m = 0; m < 2; ++m)
#pragma unroll
      for (int n = 0; n < 4; ++n)
        acc[m][n] = __builtin_amdgcn_mfma_f32_16x16x32_bf16(a[m], b[n], acc[m][n], 0, 0, 0);
    __syncthreads();
  }

#pragma unroll
  for (int m = 0; m < 2; ++m) {
    int r0 = rowBase + wr * 32 + m * 16 + ((lane >> 4) * 4);
    float q2v[4], qsv[4];
#pragma unroll
    for (int r = 0; r < 4; ++r) { q2v[r] = q2[r0 + r]; qsv[r] = qs[r0 + r]; }
#pragma unroll
    for (int n = 0; n < 4; ++n) {
      int c = wc * 64 + n * 16 + (lane & 15);
      if (c < N_WAY) {
        float pp = p2[c], pss = ps[c];
#pragma unroll
        for (int r = 0; r < 4; ++r) {
          float sq = q2v[r] + pp - 2.f * acc[m][n][r]
                   + 2e-6f * (qsv[r] - pss) + (float)D_EMB * 1e-12f;
          out[(size_t)(r0 + r) * N_WAY + c] = -sqrtf(fmaxf(sq, 0.f));
        }
      }
    }
  }
}

// ---------------- launch -----------------------------------------------------
extern "C" void kernel_launch(void* const* d_in, const int* in_sizes, int n_in,
                              void* d_out, int out_size, void* d_ws, size_t ws_size,
                              hipStream_t stream) {
  const float* simg = (const float*)d_in[0];
  // d_in[1] = support_labels: labels = i/10 already sorted -> identity argsort
  const float* qimg = (const float*)d_in[2];
  const float* W    = (const float*)d_in[3];
  const float* bias = (const float*)d_in[4];
  float* out = (float*)d_out;

  char* ws = (char*)d_ws;
  u16*   Wt  = (u16*)(ws);                 //  8,388,608 B
  float* Z   = (float*)(ws + 8388608);     // 37,748,736 B
  u16*   Zq  = (u16*)(ws + 46137344);      // 16,777,216 B
  float* Ztf = (float*)(ws + 62914560);    //    524,288 B
  u16*   Ztb = (u16*)(ws + 63438848);      //    262,144 B
  float* q2  = (float*)(ws + 63700992);    //     32,768 B
  float* qs  = (float*)(ws + 63733760);    //     32,768 B
  float* p2  = (float*)(ws + 63766528);    //        512 B
  float* ps  = (float*)(ws + 63767040);    //        512 B

  hipLaunchKernelGGL(wt_k,    dim3(128, 32), dim3(256), 0, stream, W, Wt);
  hipLaunchKernelGGL(gemm1_k, dim3(8, 144),  dim3(256), 0, stream, qimg, simg, Wt, bias, Z);
  hipLaunchKernelGGL(proto_k, dim3(512),     dim3(256), 0, stream, Z, Ztf);
  hipLaunchKernelGGL(stats_k, dim3(8192),    dim3(256), 0, stream, Z, Zq, q2, qs);
  hipLaunchKernelGGL(stats_k, dim3(128),     dim3(256), 0, stream, Ztf, Ztb, p2, ps);
  hipLaunchKernelGGL(gemm2_k, dim3(128),     dim3(256), 0, stream, Zq, Ztb, q2, qs, p2, ps, out);
}

// Round 5
// 170.407 us; speedup vs baseline: 1.3377x; 1.1076x over previous
//
#include <hip/hip_runtime.h>

// PrototypicalNetworkModel on MI355X.
// Pipeline: W^T->bf16 transpose | bf16-MFMA GEMM (query+support stacked,
// 64x128 tile, single-buffer 2-barrier loop, gload_lds B + reg-staged cvt A,
// T2 XOR-swizzled LDS, BK=64, XCD-aware col-fastest block swizzle) |
// prototype median+mean | per-row stats + bf16 cast | cross-GEMM with fused
// sqrt-distance epilogue.

typedef unsigned short u16;
typedef __attribute__((ext_vector_type(4))) unsigned short u16x4;
typedef __attribute__((ext_vector_type(8))) unsigned short u16x8;
typedef __attribute__((ext_vector_type(8))) short bf16x8;   // 8 bf16 (4 VGPRs)
typedef __attribute__((ext_vector_type(4))) float f32x4;

#define N_QUERY 8192
#define F_IN    4096
#define D_EMB   1024
#define N_SUP   1000
#define N_WAY   100
#define BK      64

__device__ __forceinline__ u16 f2b(float f) {   // f32 -> bf16 RNE
  unsigned int u = __builtin_bit_cast(unsigned int, f);
  u += 0x7FFFu + ((u >> 16) & 1u);
  return (u16)(u >> 16);
}

#define GLB_PTR(p) ((const __attribute__((address_space(1))) unsigned int*)(p))
#define LDS_PTR(p) ((__attribute__((address_space(3))) unsigned int*)(p))

// ---------------- W [4096][1024] f32 -> Wt [1024][4096] bf16 ----------------
__global__ __launch_bounds__(256) void wt_k(const float* __restrict__ W,
                                            u16* __restrict__ Wt) {
  __shared__ float tile[32][33];
  int kb = blockIdx.x * 32, nb = blockIdx.y * 32;
  int tx = threadIdx.x & 31, ty = threadIdx.x >> 5;
#pragma unroll
  for (int i = 0; i < 4; ++i) {
    int k = ty + i * 8;
    tile[k][tx] = W[(size_t)(kb + k) * D_EMB + nb + tx];
  }
  __syncthreads();
#pragma unroll
  for (int i = 0; i < 4; ++i) {
    int n = ty + i * 8;
    Wt[(size_t)(nb + n) * F_IN + kb + tx] = f2b(tile[tx][n]);
  }
}

// ---------------- GEMM1: Z[9216][1024] = A[9216][4096] @ W + b -------------
// 64x128 tile, 4 waves as 2x2 (each wave 32x64 output), SINGLE-buffer LDS
// (24 KB -> ~5-6 blocks/CU; implicit wave-level overlap does the hiding).
// LDS rows are 64 bf16 = 128B, T2 storage swizzle:
//   storage_byte = row*128 + (col_byte ^ ((row&7)<<4))
// B staged via global_load_lds (linear dest, inverse-swizzled global source).
// A (f32): loads issued FIRST so cvt waits vmcnt(4), not the whole queue.
__global__ __launch_bounds__(256) void gemm1_k(
    const float* __restrict__ qimg, const float* __restrict__ simg,
    const u16* __restrict__ Wt, const float* __restrict__ bias,
    float* __restrict__ Z) {
  __shared__ __align__(16) u16 As[64 * BK];     //  8 KB
  __shared__ __align__(16) u16 Bs[128 * BK];    // 16 KB
  const int tid  = threadIdx.x;
  const int lane = tid & 63, wid = tid >> 6;
  const int wr = wid >> 1, wc = wid & 1;
  // XCD-aware swizzle: grid (8 cols, 144 rows); 1152 % 8 == 0 -> simple form.
  // XCD k gets 18 consecutive row-panels, col varying fastest -> the 8 blocks
  // sharing an A row-panel are temporally adjacent on one XCD's L2.
  int lin = blockIdx.x + (blockIdx.y << 3);
  int swz = (lin & 7) * 144 + (lin >> 3);
  const int rowBase = (swz >> 3) * 64;
  const int colBase = (swz & 7) * 128;

  // ---- A staging: 2 chunks of 16B (8 bf16 <- 8 f32) per thread ----
  const float* asrc[2];
  int aw[2];
#pragma unroll
  for (int i = 0; i < 2; ++i) {
    int g = i * 256 + tid;                    // chunk id, 512 total (64 rows x 8)
    int row = g >> 3;
    int colb = ((g & 7) << 4) ^ ((row & 7) << 4);   // inverse swizzle (involution)
    int grow = rowBase + row;
    int sr = grow - N_QUERY; if (sr < 0) sr = 0; if (sr > N_SUP - 1) sr = N_SUP - 1;
    const float* base = (grow < N_QUERY) ? qimg + (size_t)grow * F_IN
                                         : simg + (size_t)sr * F_IN;
    asrc[i] = base + (colb >> 1);
    aw[i] = g * 8;
  }
  // ---- B staging: 4 gload_lds chunks per thread ----
  const u16* bsrc[4];
  unsigned bldsoff[4];                        // wave-uniform LDS byte base
#pragma unroll
  for (int i = 0; i < 4; ++i) {
    int g = i * 256 + tid;                    // 1024 chunks (128 rows x 8)
    int n = g >> 3;
    int kb = ((g & 7) << 4) ^ ((n & 7) << 4);
    bsrc[i] = Wt + (size_t)(colBase + n) * F_IN + (kb >> 1);
    bldsoff[i] = i * 4096 + wid * 1024;
  }
  // ---- fragment read offsets (u16 index, ks=0); ks toggles bit5 ----
  int aoff[2], boff[4];
#pragma unroll
  for (int m = 0; m < 2; ++m) {
    int row = wr * 32 + m * 16 + (lane & 15);
    aoff[m] = (row * 128 + (((lane >> 4) << 4) ^ ((row & 7) << 4))) >> 1;
  }
#pragma unroll
  for (int n = 0; n < 4; ++n) {
    int row = wc * 64 + n * 16 + (lane & 15);
    boff[n] = (row * 128 + (((lane >> 4) << 4) ^ ((row & 7) << 4))) >> 1;
  }

  f32x4 acc[2][4] = {};

#pragma unroll 1
  for (int kt = 0; kt < F_IN / BK; ++kt) {
    // A f32 loads first (cvt then needs only vmcnt(4))
    const float* p0 = asrc[0] + kt * BK;
    const float* p1 = asrc[1] + kt * BK;
    float4 v00 = *(const float4*)p0, v01 = *(const float4*)(p0 + 4);
    float4 v10 = *(const float4*)p1, v11 = *(const float4*)(p1 + 4);
    // B: async global->LDS, 4 x dwordx4 per thread
#pragma unroll
    for (int i = 0; i < 4; ++i)
      __builtin_amdgcn_global_load_lds(GLB_PTR(bsrc[i] + kt * BK),
                                       LDS_PTR((char*)Bs + bldsoff[i]), 16, 0, 0);
    // cvt + linear 16B ds_write
    u16x8 pk0 = { f2b(v00.x), f2b(v00.y), f2b(v00.z), f2b(v00.w),
                  f2b(v01.x), f2b(v01.y), f2b(v01.z), f2b(v01.w) };
    u16x8 pk1 = { f2b(v10.x), f2b(v10.y), f2b(v10.z), f2b(v10.w),
                  f2b(v11.x), f2b(v11.y), f2b(v11.z), f2b(v11.w) };
    *(u16x8*)&As[aw[0]] = pk0;
    *(u16x8*)&As[aw[1]] = pk1;
    __syncthreads();   // drains vmcnt (gload_lds) + lgkm (ds_write)

#pragma unroll
    for (int ks = 0; ks < 2; ++ks) {
      bf16x8 a[2], b[4];
#pragma unroll
      for (int m = 0; m < 2; ++m) a[m] = *(const bf16x8*)&As[aoff[m] ^ (ks << 5)];
#pragma unroll
      for (int n = 0; n < 4; ++n) b[n] = *(const bf16x8*)&Bs[boff[n] ^ (ks << 5)];
#pragma unroll
      for (int m = 0; m < 2; ++m)
#pragma unroll
        for (int n = 0; n < 4; ++n)
          acc[m][n] = __builtin_amdgcn_mfma_f32_16x16x32_bf16(a[m], b[n], acc[m][n], 0, 0, 0);
    }
    __syncthreads();
  }

#pragma unroll
  for (int n = 0; n < 4; ++n) {
    int c = colBase + wc * 64 + n * 16 + (lane & 15);
    float bvv = bias[c];
#pragma unroll
    for (int m = 0; m < 2; ++m) {
      int r0 = rowBase + wr * 32 + m * 16 + ((lane >> 4) * 4);
#pragma unroll
      for (int r = 0; r < 4; ++r)
        Z[(size_t)(r0 + r) * D_EMB + c] = acc[m][n][r] + bvv;
    }
  }
}

// ---------------- prototypes: z_total [128][1024] (rows >=100 zeroed) -------
__global__ __launch_bounds__(256) void proto_k(const float* __restrict__ Z,
                                               float* __restrict__ Ztf) {
  int gid = blockIdx.x * 256 + threadIdx.x;   // 128*1024 threads
  int w = gid >> 10, d = gid & 1023;
  float outv = 0.f;
  if (w < N_WAY) {
    float v[10]; float s = 0.f;
#pragma unroll
    for (int k = 0; k < 10; ++k) {
      v[k] = Z[(size_t)(N_QUERY + w * 10 + k) * D_EMB + d];
      s += v[k];
    }
#pragma unroll
    for (int a = 0; a < 9; ++a)
#pragma unroll
      for (int b2 = 0; b2 < 9; ++b2)
        if (b2 < 9 - a) {
          float lo = fminf(v[b2], v[b2 + 1]);
          float hi = fmaxf(v[b2], v[b2 + 1]);
          v[b2] = lo; v[b2 + 1] = hi;
        }
    outv = 0.5f * (v[4] + s * 0.1f);   // lower median + mean, halved
  }
  Ztf[gid] = outv;
}

// ---------------- per-row stats + bf16 cast ---------------------------------
__global__ __launch_bounds__(256) void stats_k(const float* __restrict__ in,
                                               u16* __restrict__ outb,
                                               float* __restrict__ sum2,
                                               float* __restrict__ sum1) {
  int row = blockIdx.x;
  const float* r = in + (size_t)row * D_EMB;
  int t = threadIdx.x;
  float4 v = *(const float4*)(r + t * 4);
  u16x4 u4 = { f2b(v.x), f2b(v.y), f2b(v.z), f2b(v.w) };
  *(u16x4*)(outb + (size_t)row * D_EMB + t * 4) = u4;
  float s  = v.x + v.y + v.z + v.w;
  float s2 = v.x * v.x + v.y * v.y + v.z * v.z + v.w * v.w;
#pragma unroll
  for (int off = 32; off > 0; off >>= 1) {
    s  += __shfl_down(s, off);
    s2 += __shfl_down(s2, off);
  }
  __shared__ float as1[4], as2[4];
  if ((t & 63) == 0) { as1[t >> 6] = s; as2[t >> 6] = s2; }
  __syncthreads();
  if (t == 0) {
    sum1[row] = as1[0] + as1[1] + as1[2] + as1[3];
    sum2[row] = as2[0] + as2[1] + as2[2] + as2[3];
  }
}

// ---------------- GEMM2: cross + fused distance -----------------------------
// out[q][p] = -sqrt(max(q2+p2-2*cross+2e-6*(qs-ps)+D*1e-12, 0))
#define LDA2 40
__global__ __launch_bounds__(256) void gemm2_k(
    const u16* __restrict__ Zq, const u16* __restrict__ Ztb,
    const float* __restrict__ q2, const float* __restrict__ qs,
    const float* __restrict__ p2, const float* __restrict__ ps,
    float* __restrict__ out) {
  __shared__ u16 As[64][LDA2];
  __shared__ u16 Bs[128][LDA2];
  const int tid = threadIdx.x;
  const int lane = tid & 63, wid = tid >> 6;
  const int wr = wid >> 1, wc = wid & 1;
  const int rowBase = blockIdx.x * 64;

  f32x4 acc[2][4] = {};

  for (int kt = 0; kt < D_EMB / 32; ++kt) {
    u16x8 avv;
    {
      int row = tid >> 2, kh = tid & 3;
      avv = *(const u16x8*)(Zq + (size_t)(rowBase + row) * D_EMB + kt * 32 + kh * 8);
    }
    u16x8 bvv[2];
#pragma unroll
    for (int i = 0; i < 2; ++i) {
      int u = i * 256 + tid;
      int n = u >> 2, kh = u & 3;
      bvv[i] = *(const u16x8*)(Ztb + (size_t)n * D_EMB + kt * 32 + kh * 8);
    }
    __syncthreads();
    {
      int row = tid >> 2, kh = tid & 3;
      *(u16x8*)&As[row][kh * 8] = avv;
    }
#pragma unroll
    for (int i = 0; i < 2; ++i) {
      int u = i * 256 + tid;
      int n = u >> 2, kh = u & 3;
      *(u16x8*)&Bs[n][kh * 8] = bvv[i];
    }
    __syncthreads();

    bf16x8 a[2], b[4];
#pragma unroll
    for (int m = 0; m < 2; ++m)
      a[m] = *(const bf16x8*)&As[wr * 32 + m * 16 + (lane & 15)][(lane >> 4) * 8];
#pragma unroll
    for (int n = 0; n < 4; ++n)
      b[n] = *(const bf16x8*)&Bs[wc * 64 + n * 16 + (lane & 15)][(lane >> 4) * 8];
#pragma unroll
    for (int m = 0; m < 2; ++m)
#pragma unroll
      for (int n = 0; n < 4; ++n)
        acc[m][n] = __builtin_amdgcn_mfma_f32_16x16x32_bf16(a[m], b[n], acc[m][n], 0, 0, 0);
    __syncthreads();
  }

#pragma unroll
  for (int m = 0; m < 2; ++m) {
    int r0 = rowBase + wr * 32 + m * 16 + ((lane >> 4) * 4);
    float q2v[4], qsv[4];
#pragma unroll
    for (int r = 0; r < 4; ++r) { q2v[r] = q2[r0 + r]; qsv[r] = qs[r0 + r]; }
#pragma unroll
    for (int n = 0; n < 4; ++n) {
      int c = wc * 64 + n * 16 + (lane & 15);
      if (c < N_WAY) {
        float pp = p2[c], pss = ps[c];
#pragma unroll
        for (int r = 0; r < 4; ++r) {
          float sq = q2v[r] + pp - 2.f * acc[m][n][r]
                   + 2e-6f * (qsv[r] - pss) + (float)D_EMB * 1e-12f;
          out[(size_t)(r0 + r) * N_WAY + c] = -sqrtf(fmaxf(sq, 0.f));
        }
      }
    }
  }
}

// ---------------- launch -----------------------------------------------------
extern "C" void kernel_launch(void* const* d_in, const int* in_sizes, int n_in,
                              void* d_out, int out_size, void* d_ws, size_t ws_size,
                              hipStream_t stream) {
  const float* simg = (const float*)d_in[0];
  // d_in[1] = support_labels: labels = i/10 already sorted -> identity argsort
  const float* qimg = (const float*)d_in[2];
  const float* W    = (const float*)d_in[3];
  const float* bias = (const float*)d_in[4];
  float* out = (float*)d_out;

  char* ws = (char*)d_ws;
  u16*   Wt  = (u16*)(ws);                 //  8,388,608 B
  float* Z   = (float*)(ws + 8388608);     // 37,748,736 B
  u16*   Zq  = (u16*)(ws + 46137344);      // 16,777,216 B
  float* Ztf = (float*)(ws + 62914560);    //    524,288 B
  u16*   Ztb = (u16*)(ws + 63438848);      //    262,144 B
  float* q2  = (float*)(ws + 63700992);    //     32,768 B
  float* qs  = (float*)(ws + 63733760);    //     32,768 B
  float* p2  = (float*)(ws + 63766528);    //        512 B
  float* ps  = (float*)(ws + 63767040);    //        512 B

  hipLaunchKernelGGL(wt_k,    dim3(128, 32), dim3(256), 0, stream, W, Wt);
  hipLaunchKernelGGL(gemm1_k, dim3(8, 144),  dim3(256), 0, stream, qimg, simg, Wt, bias, Z);
  hipLaunchKernelGGL(proto_k, dim3(512),     dim3(256), 0, stream, Z, Ztf);
  hipLaunchKernelGGL(stats_k, dim3(8192),    dim3(256), 0, stream, Z, Zq, q2, qs);
  hipLaunchKernelGGL(stats_k, dim3(128),     dim3(256), 0, stream, Ztf, Ztb, p2, ps);
  hipLaunchKernelGGL(gemm2_k, dim3(128),     dim3(256), 0, stream, Zq, Ztb, q2, qs, p2, ps, out);
}